// Round 8
// baseline (413.550 us; speedup 1.0000x reference)
//
#include <hip/hip_runtime.h>
#include <hip/hip_fp16.h>
#include <math.h>

// ---------------------------------------------------------------------------
// GCN: 3x (MFMA-fp16 GEMM -> sym-normalized neighbor aggregate) with SiLU,
// then per-graph max+mean pool and log_softmax.
// CSR build = 2-pass bucket sort (256 nodes/bucket) -- round-6 structure.
// Round 7/8: XCD-pinned feature-sliced aggregation.
//   Table stored as Hs[slice][node][12] fp16 (24B per row-slice); slice s
//   is processed only by blocks with blockIdx%8==s, which land on XCD s
//   (round-robin dispatch heuristic) -> each XCD's 4MB L2 holds its 2.4MB
//   slice and the random gathers become L2 hits. adj reads + output stores
//   are nontemporal so streaming traffic doesn't evict the pinned slice.
//   (Nontemporal builtins need clang ext-vector types, NOT HIP float4.)
// ---------------------------------------------------------------------------

typedef _Float16 f16x8 __attribute__((ext_vector_type(8)));
typedef _Float16 f16x4 __attribute__((ext_vector_type(4)));
typedef float f32x4 __attribute__((ext_vector_type(4)));

static __device__ __forceinline__ float silu_f(float v) {
    return v / (1.0f + __expf(-v));
}

// --- int64-vs-int32 input detection -----------------------------------------
__global__ __launch_bounds__(256) void k_detect(const int* __restrict__ raw,
                                                int* __restrict__ flag) {
    __shared__ int anynz;
    if (threadIdx.x == 0) anynz = 0;
    __syncthreads();
    if (raw[2 * threadIdx.x + 1] != 0) anynz = 1;  // benign race, same value
    __syncthreads();
    if (threadIdx.x == 0) *flag = (anynz ? 0 : 1); // 1 => int64
}

__global__ __launch_bounds__(256) void k_convert(const int* __restrict__ raw,
                                                 int* __restrict__ out,
                                                 const int* __restrict__ flag,
                                                 int count) {
    int i = blockIdx.x * 256 + threadIdx.x;
    if (i < count) out[i] = flag[0] ? raw[2 * i] : raw[i];
}

// --- CSR pass 1: bucket histogram (bucket = dst>>8, <=512 buckets) -----------
__global__ __launch_bounds__(512) void k_p1hist(const int* __restrict__ dst,
                                                int* __restrict__ bcnt,
                                                int E, int nbuk) {
    __shared__ int hs[512];
    const int t = threadIdx.x;
    hs[t] = 0;
    __syncthreads();
    const int base = blockIdx.x * 8192;
    const int lim = min(base + 8192, E);
    for (int j = base + t; j < lim; j += 512)
        atomicAdd(&hs[dst[j] >> 8], 1);
    __syncthreads();
    if (t < nbuk && hs[t]) atomicAdd(&bcnt[t], hs[t]);
}

// --- CSR pass 1b: exclusive scan of bucket counts -> bstart ------------------
__global__ __launch_bounds__(512) void k_bscan(const int* __restrict__ bcnt,
                                               int* __restrict__ bstart,
                                               int nbuk, int E) {
    __shared__ int lds[512];
    int t = threadIdx.x;
    int v = (t < nbuk) ? bcnt[t] : 0;
    lds[t] = v;
    __syncthreads();
    for (int off = 1; off < 512; off <<= 1) {
        int y = (t >= off) ? lds[t - off] : 0;
        __syncthreads();
        lds[t] += y;
        __syncthreads();
    }
    if (t < nbuk) bstart[t] = lds[t] - v;
    if (t == 0) bstart[nbuk] = E;
}

// --- CSR pass 2: bucket scatter, block-staged ---------------------------------
__global__ __launch_bounds__(512) void k_p2scatter(const int* __restrict__ e32,
                                                   const int* __restrict__ bstart,
                                                   int* __restrict__ gcursor,
                                                   unsigned* __restrict__ ebuk,
                                                   int E, int nbuk) {
    __shared__ int hs[512], sc[512], lexcl[512], pl[512], gb[512];
    __shared__ unsigned stg[8192];
    __shared__ unsigned short stb[8192];
    const int t = threadIdx.x;
    const int base = blockIdx.x * 8192;
    const int len = min(8192, E - base);
    const int* __restrict__ dstp = e32 + E;

    hs[t] = 0;
    __syncthreads();
    for (int j = t; j < len; j += 512)
        atomicAdd(&hs[dstp[base + j] >> 8], 1);
    __syncthreads();

    int cv = (t < nbuk) ? hs[t] : 0;
    sc[t] = cv;
    __syncthreads();
    for (int off = 1; off < 512; off <<= 1) {
        int y = (t >= off) ? sc[t - off] : 0;
        __syncthreads();
        sc[t] += y;
        __syncthreads();
    }
    int ex = sc[t] - cv;
    if (t < nbuk) {
        lexcl[t] = ex;
        pl[t] = ex;
        gb[t] = cv ? atomicAdd(&gcursor[t], cv) : 0;
    }
    __syncthreads();

    for (int j = t; j < len; j += 512) {
        int d = dstp[base + j];
        int s = e32[base + j];
        int b = d >> 8;
        int slot = atomicAdd(&pl[b], 1);
        stg[slot] = ((unsigned)s << 8) | (unsigned)(d & 255);
        stb[slot] = (unsigned short)b;
    }
    __syncthreads();

    for (int s2 = t; s2 < len; s2 += 512) {
        int b = stb[s2];
        int gpos = bstart[b] + gb[b] + (s2 - lexcl[b]);
        ebuk[gpos] = stg[s2];
    }
}

// --- CSR pass 3: per-bucket counting sort -> adj, rowptr, dinv ----------------
__global__ __launch_bounds__(256) void k_p3sort(const unsigned* __restrict__ ebuk,
                                                const int* __restrict__ bstart,
                                                int* __restrict__ adj,
                                                int* __restrict__ rowptr,
                                                float* __restrict__ dinv,
                                                int n, int E) {
    const int b = blockIdx.x;
    const int t = threadIdx.x;
    const int s0 = bstart[b], s1 = bstart[b + 1];
    __shared__ int cs[256], pl[256];
    cs[t] = 0;
    __syncthreads();
    for (int j = s0 + t; j < s1; j += 256)
        atomicAdd(&cs[ebuk[j] & 255], 1);
    __syncthreads();
    int cv = cs[t];
    pl[t] = cv;
    __syncthreads();
    for (int off = 1; off < 256; off <<= 1) {
        int y = (t >= off) ? pl[t - off] : 0;
        __syncthreads();
        pl[t] += y;
        __syncthreads();
    }
    int ex = pl[t] - cv;
    __syncthreads();
    pl[t] = ex;
    int node = (b << 8) + t;
    if (node < n) {
        rowptr[node] = s0 + ex;
        dinv[node] = rsqrtf((float)cv + 1.0f);  // +1 self loop
    }
    if (b == 0 && t == 0) rowptr[n] = E;
    __syncthreads();
    for (int j = s0 + t; j < s1; j += 256) {
        unsigned p = ebuk[j];
        int slot = atomicAdd(&pl[p & 255], 1);
        adj[s0 + slot] = (int)(p >> 8);
    }
}

// --- per-graph boundaries (batch is sorted) -----------------------------------
__global__ __launch_bounds__(256) void k_gstart(const int* __restrict__ batch,
                                                int* __restrict__ gstart,
                                                int n, int G) {
    int t = threadIdx.x;
    if (t > G) return;
    int lo = 0, hi = n;
    while (lo < hi) {
        int mid = (lo + hi) >> 1;
        if (batch[mid] < t) lo = mid + 1; else hi = mid;
    }
    gstart[t] = lo;
}

// --- W transpose + fp16 convert: WT[n][k] = fp16(W[k][n]) ---------------------
__global__ __launch_bounds__(256) void k_wt(const float* __restrict__ W,
                                            __half* __restrict__ WT, int fout) {
    int idx = blockIdx.x * 256 + threadIdx.x;
    if (idx < fout * 96) {
        int nn = idx / 96, kk = idx - nn * 96;
        WT[idx] = __float2half(W[kk * fout + nn]);
    }
}

// --- MFMA GEMM: Hs[sl][r][SLICEW] = fp16( dinv[r] * (X[r,:96] @ W) ) ----------
// LDS-free; A/B share identical per-lane k-addressing so the k->slot map
// cancels. Epilogue writes the SLICED table layout.
template <int FOUT, int SLICEW>
__global__ __launch_bounds__(256) void k_gemm_mfma(const float* __restrict__ X,
                                                   const __half* __restrict__ WT,
                                                   const float* __restrict__ dinv,
                                                   __half* __restrict__ Hs, int n) {
    const int l = threadIdx.x & 63;
    const int w = threadIdx.x >> 6;
    const int row0 = blockIdx.x * 64 + w * 16;
    const int lr = l & 15, lg = l >> 4;
    constexpr int NT = FOUT / 16;

    f16x8 bfrag[NT][3];
    #pragma unroll
    for (int t = 0; t < NT; ++t)
        #pragma unroll
        for (int kk = 0; kk < 3; ++kk)
            bfrag[t][kk] = *(const f16x8*)&WT[(t * 16 + lr) * 96 + kk * 32 + lg * 8];

    f32x4 acc[NT];
    #pragma unroll
    for (int t = 0; t < NT; ++t) acc[t] = (f32x4){0.f, 0.f, 0.f, 0.f};

    int arow = row0 + lr;
    int arow_c = arow < n ? arow : n - 1;
    const float* xr = X + (size_t)arow_c * 96;

    #pragma unroll
    for (int kk = 0; kk < 3; ++kk) {
        float4 u0 = *(const float4*)&xr[kk * 32 + lg * 8];
        float4 u1 = *(const float4*)&xr[kk * 32 + lg * 8 + 4];
        f16x8 af;
        af[0] = (_Float16)u0.x; af[1] = (_Float16)u0.y;
        af[2] = (_Float16)u0.z; af[3] = (_Float16)u0.w;
        af[4] = (_Float16)u1.x; af[5] = (_Float16)u1.y;
        af[6] = (_Float16)u1.z; af[7] = (_Float16)u1.w;
        #pragma unroll
        for (int t = 0; t < NT; ++t)
            acc[t] = __builtin_amdgcn_mfma_f32_16x16x32_f16(af, bfrag[t][kk], acc[t], 0, 0, 0);
    }

    // C/D: col = t*16+lr, row = row0 + lg*4 + i; write sliced layout
    #pragma unroll
    for (int i = 0; i < 4; ++i) {
        int r = row0 + lg * 4 + i;
        if (r < n) {
            float dv = dinv[r];
            #pragma unroll
            for (int t = 0; t < NT; ++t) {
                int cc = t * 16 + lr;
                int sl = cc / SLICEW;
                int jj = cc - sl * SLICEW;
                Hs[((size_t)sl * n + r) * SLICEW + jj] = __float2half(acc[t][i] * dv);
            }
        }
    }
}

// --- sliced aggregation, F=96: slice = blockIdx%8 (XCD-pinned) ----------------
// Wave = 8 nodes x 8 chains. Lane gathers its chain's 24B row-slice
// (3 x f16x4), accumulates 12 feats with mix-FMA (w = tail mask), then
// 3 shfl_xor rounds reduce the 8 chains of each node.
template <bool SILU>
__global__ __launch_bounds__(256) void k_agg96s(const __half* __restrict__ Hs,
                                                const float* __restrict__ dinv,
                                                const int* __restrict__ rowptr,
                                                const int* __restrict__ adj,
                                                const float* __restrict__ bias,
                                                float* __restrict__ OUT, int n) {
    const int s = blockIdx.x & 7;
    const int nb = blockIdx.x >> 3;
    const int l = threadIdx.x & 63;
    const int c = l & 7;
    const int ni = nb * 32 + (threadIdx.x >> 6) * 8 + (l >> 3);
    const int nic = ni < n ? ni : n - 1;
    const float dn = dinv[nic];
    const int e0 = rowptr[nic];
    const int deg = rowptr[nic + 1] - e0;
    const int cnt = deg + 1;  // +self
    const __half* __restrict__ tb = Hs + (size_t)s * n * 12;

    float acc[12];
    #pragma unroll
    for (int i = 0; i < 12; ++i) acc[i] = 0.f;

    for (int k0 = 0; k0 < cnt; k0 += 8) {
        int idx = k0 + c;
        int src = nic;                       // idx==0 -> self row
        int oe = idx - 1;
        if (oe >= 0 && oe < deg)
            src = __builtin_nontemporal_load(adj + e0 + oe);
        float wv = (idx < cnt) ? 1.f : 0.f;
        const f16x4* p = (const f16x4*)(tb + (size_t)src * 12);
        f16x4 v0 = p[0], v1 = p[1], v2 = p[2];
        #pragma unroll
        for (int i = 0; i < 4; ++i) {
            acc[i]     = fmaf((float)v0[i], wv, acc[i]);
            acc[4 + i] = fmaf((float)v1[i], wv, acc[4 + i]);
            acc[8 + i] = fmaf((float)v2[i], wv, acc[8 + i]);
        }
    }

    #pragma unroll
    for (int i = 0; i < 12; ++i) {
        acc[i] += __shfl_xor(acc[i], 1, 64);
        acc[i] += __shfl_xor(acc[i], 2, 64);
        acc[i] += __shfl_xor(acc[i], 4, 64);
    }

    if (c == 0 && ni < n) {
        const float4* bv = (const float4*)(bias + s * 12);
        float4 b0 = bv[0], b1 = bv[1], b2 = bv[2];
        float o[12];
        o[0] = acc[0] * dn + b0.x;  o[1] = acc[1] * dn + b0.y;
        o[2] = acc[2] * dn + b0.z;  o[3] = acc[3] * dn + b0.w;
        o[4] = acc[4] * dn + b1.x;  o[5] = acc[5] * dn + b1.y;
        o[6] = acc[6] * dn + b1.z;  o[7] = acc[7] * dn + b1.w;
        o[8] = acc[8] * dn + b2.x;  o[9] = acc[9] * dn + b2.y;
        o[10] = acc[10] * dn + b2.z; o[11] = acc[11] * dn + b2.w;
        if (SILU) {
            #pragma unroll
            for (int j = 0; j < 12; ++j) o[j] = silu_f(o[j]);
        }
        f32x4* op = (f32x4*)(OUT + (size_t)ni * 96 + s * 12);
        __builtin_nontemporal_store((f32x4){o[0], o[1], o[2], o[3]}, op);
        __builtin_nontemporal_store((f32x4){o[4], o[5], o[6], o[7]}, op + 1);
        __builtin_nontemporal_store((f32x4){o[8], o[9], o[10], o[11]}, op + 2);
    }
}

// --- sliced aggregation, F=32: 4 feats (8B) per slice --------------------------
__global__ __launch_bounds__(256) void k_agg32s(const __half* __restrict__ Hs,
                                                const float* __restrict__ dinv,
                                                const int* __restrict__ rowptr,
                                                const int* __restrict__ adj,
                                                const float* __restrict__ bias,
                                                float* __restrict__ OUT, int n) {
    const int s = blockIdx.x & 7;
    const int nb = blockIdx.x >> 3;
    const int l = threadIdx.x & 63;
    const int c = l & 7;
    const int ni = nb * 32 + (threadIdx.x >> 6) * 8 + (l >> 3);
    const int nic = ni < n ? ni : n - 1;
    const float dn = dinv[nic];
    const int e0 = rowptr[nic];
    const int deg = rowptr[nic + 1] - e0;
    const int cnt = deg + 1;
    const __half* __restrict__ tb = Hs + (size_t)s * n * 4;

    float acc[4] = {0.f, 0.f, 0.f, 0.f};

    for (int k0 = 0; k0 < cnt; k0 += 8) {
        int idx = k0 + c;
        int src = nic;
        int oe = idx - 1;
        if (oe >= 0 && oe < deg)
            src = __builtin_nontemporal_load(adj + e0 + oe);
        float wv = (idx < cnt) ? 1.f : 0.f;
        f16x4 v = *(const f16x4*)(tb + (size_t)src * 4);
        #pragma unroll
        for (int i = 0; i < 4; ++i) acc[i] = fmaf((float)v[i], wv, acc[i]);
    }

    #pragma unroll
    for (int i = 0; i < 4; ++i) {
        acc[i] += __shfl_xor(acc[i], 1, 64);
        acc[i] += __shfl_xor(acc[i], 2, 64);
        acc[i] += __shfl_xor(acc[i], 4, 64);
    }

    if (c == 0 && ni < n) {
        float4 bv = *(const float4*)(bias + s * 4);
        f32x4 o = {acc[0] * dn + bv.x, acc[1] * dn + bv.y,
                   acc[2] * dn + bv.z, acc[3] * dn + bv.w};
        __builtin_nontemporal_store(o, (f32x4*)(OUT + (size_t)ni * 32 + s * 4));
    }
}

// --- per-graph max+mean pool (block per graph) --------------------------------
__global__ __launch_bounds__(256) void k_pool(const float* __restrict__ A,
                                              const int* __restrict__ gstart,
                                              float* __restrict__ pooled) {
    int g = blockIdx.x;
    int s0 = gstart[g], s1 = gstart[g + 1];
    int c = threadIdx.x & 31, k = threadIdx.x >> 5;
    float mx = -INFINITY, sm = 0.f;
    for (int nidx = s0 + k; nidx < s1; nidx += 8) {
        float v = A[(size_t)nidx * 32 + c];
        mx = fmaxf(mx, v);
        sm += v;
    }
    __shared__ float smx[8][32], ssm[8][32];
    smx[k][c] = mx;
    ssm[k][c] = sm;
    __syncthreads();
    if (threadIdx.x < 32) {
        float M = smx[0][c], S = ssm[0][c];
        #pragma unroll
        for (int kk = 1; kk < 8; ++kk) {
            M = fmaxf(M, smx[kk][c]);
            S += ssm[kk][c];
        }
        int cnt = s1 - s0;
        pooled[g * 64 + c] = M;
        pooled[g * 64 + 32 + c] = S / fmaxf((float)cnt, 1.0f);
    }
}

// --- row log_softmax over 64 values -------------------------------------------
__global__ __launch_bounds__(64) void k_lsm(const float* __restrict__ pooled,
                                            float* __restrict__ out) {
    int g = blockIdx.x;
    int l = threadIdx.x;
    float v = pooled[g * 64 + l];
    float m = v;
    #pragma unroll
    for (int o = 32; o > 0; o >>= 1) m = fmaxf(m, __shfl_xor(m, o, 64));
    float e = __expf(v - m);
    float s = e;
    #pragma unroll
    for (int o = 32; o > 0; o >>= 1) s += __shfl_xor(s, o, 64);
    out[g * 64 + l] = v - m - __logf(s);
}

// ---------------------------------------------------------------------------
extern "C" void kernel_launch(void* const* d_in, const int* in_sizes, int n_in,
                              void* d_out, int out_size, void* d_ws, size_t ws_size,
                              hipStream_t stream) {
    const float* x  = (const float*)d_in[0];
    const float* W0 = (const float*)d_in[1];
    const float* b0 = (const float*)d_in[2];
    const float* W1 = (const float*)d_in[3];
    const float* b1 = (const float*)d_in[4];
    const float* W2 = (const float*)d_in[5];
    const float* b2 = (const float*)d_in[6];
    const int* ei_raw    = (const int*)d_in[7];
    const int* batch_raw = (const int*)d_in[8];

    const int N = in_sizes[0] / 96;
    const int E = in_sizes[7] / 2;
    const int G = out_size / 64;
    const int NBUK = (N + 255) >> 8;          // 256 nodes/bucket, <=512 buckets
    float* out = (float*)d_out;

    char* ws = (char*)d_ws;
    size_t off = 0;
    auto alloc = [&](size_t bytes) -> void* {
        void* p = ws + off;
        off += (bytes + 255) & ~(size_t)255;
        return p;
    };
    float*    A32     = (float*)alloc((size_t)N * 96 * 4);    // agg output (fp32)
    __half*   Hs96    = (__half*)alloc((size_t)N * 96 * 2);   // sliced shat table
    __half*   Hs32    = (__half*)alloc((size_t)N * 32 * 2);   // layer-2 sliced shat
    float*    D32     = (float*)alloc((size_t)N * 32 * 4);    // layer-2 agg out
    int*      e32     = (int*)alloc((size_t)2 * E * 4);
    int*      batch32 = (int*)alloc((size_t)N * 4);
    float*    dinv    = (float*)alloc((size_t)N * 4);
    int*      rowptr  = (int*)alloc((size_t)(N + 1) * 4);
    int*      adj     = (int*)alloc((size_t)E * 4);
    unsigned* ebuk    = (unsigned*)alloc((size_t)E * 4);      // bucket-sorted packed edges
    int*      bcnt    = (int*)alloc(512 * 4);
    int*      bstart  = (int*)alloc(513 * 4);
    int*      gcursor = (int*)alloc(512 * 4);
    int*      flag    = (int*)alloc(256);
    int*      gstart  = (int*)alloc((size_t)(G + 1) * 4);
    float*    pooled  = (float*)alloc((size_t)G * 64 * 4);
    __half*   WT0     = (__half*)alloc((size_t)96 * 96 * 2);  // W^T fp16
    __half*   WT1     = (__half*)alloc((size_t)96 * 96 * 2);
    __half*   WT2     = (__half*)alloc((size_t)32 * 96 * 2);

    hipMemsetAsync(bcnt, 0, 512 * 4, stream);
    hipMemsetAsync(gcursor, 0, 512 * 4, stream);

    // index dtype normalize
    k_detect<<<1, 256, 0, stream>>>(ei_raw, flag);
    k_convert<<<(2 * E + 255) / 256, 256, 0, stream>>>(ei_raw, e32, flag, 2 * E);
    k_convert<<<(N + 255) / 256, 256, 0, stream>>>(batch_raw, batch32, flag, N);

    // weight transpose+convert (tiny)
    k_wt<<<(96 * 96 + 255) / 256, 256, 0, stream>>>(W0, WT0, 96);
    k_wt<<<(96 * 96 + 255) / 256, 256, 0, stream>>>(W1, WT1, 96);
    k_wt<<<(32 * 96 + 255) / 256, 256, 0, stream>>>(W2, WT2, 32);

    // CSR via bucket sort
    const int P2B = (E + 8191) / 8192;
    k_p1hist<<<P2B, 512, 0, stream>>>(e32 + E, bcnt, E, NBUK);
    k_bscan<<<1, 512, 0, stream>>>(bcnt, bstart, NBUK, E);
    k_p2scatter<<<P2B, 512, 0, stream>>>(e32, bstart, gcursor, ebuk, E, NBUK);
    k_p3sort<<<NBUK, 256, 0, stream>>>(ebuk, bstart, adj, rowptr, dinv, N, E);
    k_gstart<<<1, 256, 0, stream>>>(batch32, gstart, N, G);

    const int GB = (N + 63) / 64;
    const int NBN = (N + 31) / 32;    // 32 nodes per agg block
    const int AGB = NBN * 8;          // x8 slices, slice = bid%8 (XCD-pinned)

    // layer 0
    k_gemm_mfma<96, 12><<<GB, 256, 0, stream>>>(x, WT0, dinv, Hs96, N);
    k_agg96s<true><<<AGB, 256, 0, stream>>>(Hs96, dinv, rowptr, adj, b0, A32, N);
    // layer 1
    k_gemm_mfma<96, 12><<<GB, 256, 0, stream>>>(A32, WT1, dinv, Hs96, N);
    k_agg96s<true><<<AGB, 256, 0, stream>>>(Hs96, dinv, rowptr, adj, b1, A32, N);
    // layer 2
    k_gemm_mfma<32, 4><<<GB, 256, 0, stream>>>(A32, WT2, dinv, Hs32, N);
    k_agg32s<<<AGB, 256, 0, stream>>>(Hs32, dinv, rowptr, adj, b2, D32, N);

    // pooling + log_softmax
    k_pool<<<G, 256, 0, stream>>>(D32, gstart, pooled);
    k_lsm<<<G, 64, 0, stream>>>(pooled, out);
}

// Round 9
// 323.775 us; speedup vs baseline: 1.2773x; 1.2773x over previous
//
#include <hip/hip_runtime.h>
#include <hip/hip_fp16.h>
#include <math.h>

// ---------------------------------------------------------------------------
// GCN: 3x (MFMA-fp16 GEMM -> sym-normalized neighbor aggregate) with SiLU,
// then per-graph max+mean pool and log_softmax.
// CSR build = 2-pass bucket sort (round-6 structure).
// Round 9: XCD-pinned feature-sliced aggregation with REPAIRED layout:
//   - tables AND agg outputs are sliced fp16, 32B-padded rows
//     T[slice][node][16] (12 real feats + 4 pad) -> slice = 3.2MB < 4MB L2;
//     blocks with blockIdx%8==s handle slice s only (round-robin XCD pin).
//   - agg writes are dense full-line, single-XCD (fixes round-8's 51MB
//     cross-XCD partial-line write amplification).
//   - gathers are 2 aligned requests (f16x8 + f16x4) per 24B row-slice.
//   - GEMM reads sliced fp16 A directly (k-permutation invariance lets A and
//     B share any k-order); no fp32->fp16 cvt, half the A traffic.
//   - layer 2 (32-feat, 6.4MB table) stays un-sliced (round-6 k_agg32).
// ---------------------------------------------------------------------------

typedef _Float16 f16x8 __attribute__((ext_vector_type(8)));
typedef _Float16 f16x4 __attribute__((ext_vector_type(4)));
typedef float f32x4 __attribute__((ext_vector_type(4)));

static __device__ __forceinline__ float silu_f(float v) {
    return v / (1.0f + __expf(-v));
}

// --- int64-vs-int32 input detection -----------------------------------------
__global__ __launch_bounds__(256) void k_detect(const int* __restrict__ raw,
                                                int* __restrict__ flag) {
    __shared__ int anynz;
    if (threadIdx.x == 0) anynz = 0;
    __syncthreads();
    if (raw[2 * threadIdx.x + 1] != 0) anynz = 1;  // benign race, same value
    __syncthreads();
    if (threadIdx.x == 0) *flag = (anynz ? 0 : 1); // 1 => int64
}

__global__ __launch_bounds__(256) void k_convert(const int* __restrict__ raw,
                                                 int* __restrict__ out,
                                                 const int* __restrict__ flag,
                                                 int count) {
    int i = blockIdx.x * 256 + threadIdx.x;
    if (i < count) out[i] = flag[0] ? raw[2 * i] : raw[i];
}

// --- CSR pass 1: bucket histogram (bucket = dst>>8, <=512 buckets) -----------
__global__ __launch_bounds__(512) void k_p1hist(const int* __restrict__ dst,
                                                int* __restrict__ bcnt,
                                                int E, int nbuk) {
    __shared__ int hs[512];
    const int t = threadIdx.x;
    hs[t] = 0;
    __syncthreads();
    const int base = blockIdx.x * 8192;
    const int lim = min(base + 8192, E);
    for (int j = base + t; j < lim; j += 512)
        atomicAdd(&hs[dst[j] >> 8], 1);
    __syncthreads();
    if (t < nbuk && hs[t]) atomicAdd(&bcnt[t], hs[t]);
}

// --- CSR pass 1b: exclusive scan of bucket counts -> bstart ------------------
__global__ __launch_bounds__(512) void k_bscan(const int* __restrict__ bcnt,
                                               int* __restrict__ bstart,
                                               int nbuk, int E) {
    __shared__ int lds[512];
    int t = threadIdx.x;
    int v = (t < nbuk) ? bcnt[t] : 0;
    lds[t] = v;
    __syncthreads();
    for (int off = 1; off < 512; off <<= 1) {
        int y = (t >= off) ? lds[t - off] : 0;
        __syncthreads();
        lds[t] += y;
        __syncthreads();
    }
    if (t < nbuk) bstart[t] = lds[t] - v;
    if (t == 0) bstart[nbuk] = E;
}

// --- CSR pass 2: bucket scatter, block-staged ---------------------------------
__global__ __launch_bounds__(512) void k_p2scatter(const int* __restrict__ e32,
                                                   const int* __restrict__ bstart,
                                                   int* __restrict__ gcursor,
                                                   unsigned* __restrict__ ebuk,
                                                   int E, int nbuk) {
    __shared__ int hs[512], sc[512], lexcl[512], pl[512], gb[512];
    __shared__ unsigned stg[8192];
    __shared__ unsigned short stb[8192];
    const int t = threadIdx.x;
    const int base = blockIdx.x * 8192;
    const int len = min(8192, E - base);
    const int* __restrict__ dstp = e32 + E;

    hs[t] = 0;
    __syncthreads();
    for (int j = t; j < len; j += 512)
        atomicAdd(&hs[dstp[base + j] >> 8], 1);
    __syncthreads();

    int cv = (t < nbuk) ? hs[t] : 0;
    sc[t] = cv;
    __syncthreads();
    for (int off = 1; off < 512; off <<= 1) {
        int y = (t >= off) ? sc[t - off] : 0;
        __syncthreads();
        sc[t] += y;
        __syncthreads();
    }
    int ex = sc[t] - cv;
    if (t < nbuk) {
        lexcl[t] = ex;
        pl[t] = ex;
        gb[t] = cv ? atomicAdd(&gcursor[t], cv) : 0;
    }
    __syncthreads();

    for (int j = t; j < len; j += 512) {
        int d = dstp[base + j];
        int s = e32[base + j];
        int b = d >> 8;
        int slot = atomicAdd(&pl[b], 1);
        stg[slot] = ((unsigned)s << 8) | (unsigned)(d & 255);
        stb[slot] = (unsigned short)b;
    }
    __syncthreads();

    for (int s2 = t; s2 < len; s2 += 512) {
        int b = stb[s2];
        int gpos = bstart[b] + gb[b] + (s2 - lexcl[b]);
        ebuk[gpos] = stg[s2];
    }
}

// --- CSR pass 3: per-bucket counting sort -> adj, rowptr, dinv ----------------
__global__ __launch_bounds__(256) void k_p3sort(const unsigned* __restrict__ ebuk,
                                                const int* __restrict__ bstart,
                                                int* __restrict__ adj,
                                                int* __restrict__ rowptr,
                                                float* __restrict__ dinv,
                                                int n, int E) {
    const int b = blockIdx.x;
    const int t = threadIdx.x;
    const int s0 = bstart[b], s1 = bstart[b + 1];
    __shared__ int cs[256], pl[256];
    cs[t] = 0;
    __syncthreads();
    for (int j = s0 + t; j < s1; j += 256)
        atomicAdd(&cs[ebuk[j] & 255], 1);
    __syncthreads();
    int cv = cs[t];
    pl[t] = cv;
    __syncthreads();
    for (int off = 1; off < 256; off <<= 1) {
        int y = (t >= off) ? pl[t - off] : 0;
        __syncthreads();
        pl[t] += y;
        __syncthreads();
    }
    int ex = pl[t] - cv;
    __syncthreads();
    pl[t] = ex;
    int node = (b << 8) + t;
    if (node < n) {
        rowptr[node] = s0 + ex;
        dinv[node] = rsqrtf((float)cv + 1.0f);  // +1 self loop
    }
    if (b == 0 && t == 0) rowptr[n] = E;
    __syncthreads();
    for (int j = s0 + t; j < s1; j += 256) {
        unsigned p = ebuk[j];
        int slot = atomicAdd(&pl[p & 255], 1);
        adj[s0 + slot] = (int)(p >> 8);
    }
}

// --- per-graph boundaries (batch is sorted) -----------------------------------
__global__ __launch_bounds__(256) void k_gstart(const int* __restrict__ batch,
                                                int* __restrict__ gstart,
                                                int n, int G) {
    int t = threadIdx.x;
    if (t > G) return;
    int lo = 0, hi = n;
    while (lo < hi) {
        int mid = (lo + hi) >> 1;
        if (batch[mid] < t) lo = mid + 1; else hi = mid;
    }
    gstart[t] = lo;
}

// --- W transpose + fp16 convert: WT[n][k] = fp16(W[k][n]) ---------------------
__global__ __launch_bounds__(256) void k_wt(const float* __restrict__ W,
                                            __half* __restrict__ WT, int fout) {
    int idx = blockIdx.x * 256 + threadIdx.x;
    if (idx < fout * 96) {
        int nn = idx / 96, kk = idx - nn * 96;
        WT[idx] = __float2half(W[kk * fout + nn]);
    }
}

// --- MFMA GEMM --------------------------------------------------------------
// A: fp32 natural (ASLICED=0) or fp16 sliced 16-half rows (ASLICED=1).
// Out: sliced 16-half rows (OUTSLICED=1) or natural FOUT-stride (OUTSLICED=0).
// A and B share identical per-lane k-position addressing -> hardware k->slot
// map cancels (dot product is k-permutation invariant).
template <int FOUT, bool ASLICED, bool OUTSLICED>
__global__ __launch_bounds__(256) void k_gemm_mfma(const float* __restrict__ Xf,
                                                   const __half* __restrict__ Xh,
                                                   const __half* __restrict__ WT,
                                                   const float* __restrict__ dinv,
                                                   __half* __restrict__ Hout, int n) {
    const int l = threadIdx.x & 63;
    const int w = threadIdx.x >> 6;
    const int row0 = blockIdx.x * 64 + w * 16;
    const int lr = l & 15, lg = l >> 4;
    constexpr int NT = FOUT / 16;

    f16x8 bfrag[NT][3];
    #pragma unroll
    for (int t = 0; t < NT; ++t)
        #pragma unroll
        for (int kk = 0; kk < 3; ++kk)
            bfrag[t][kk] = *(const f16x8*)&WT[(t * 16 + lr) * 96 + kk * 32 + lg * 8];

    f32x4 acc[NT];
    #pragma unroll
    for (int t = 0; t < NT; ++t) acc[t] = (f32x4){0.f, 0.f, 0.f, 0.f};

    int arow = row0 + lr;
    int arow_c = arow < n ? arow : n - 1;  // clamp; garbage rows never stored

    #pragma unroll
    for (int kk = 0; kk < 3; ++kk) {
        f16x8 af;
        if (ASLICED) {
            // virtual k positions p=kk*32+lg*8 .. +7; 4-chunks q=p/4, q+1
            // chunk q -> slice s=q/3 (=(q*11)>>5 for q<24), j=4*(q%3)
            int q0 = 8 * kk + 2 * lg;
            int s0 = (q0 * 11) >> 5; int j0 = (q0 - 3 * s0) * 4;
            int q1 = q0 + 1;
            int s1 = (q1 * 11) >> 5; int j1 = (q1 - 3 * s1) * 4;
            f16x4 a0 = *(const f16x4*)(Xh + ((size_t)s0 * n + arow_c) * 16 + j0);
            f16x4 a1 = *(const f16x4*)(Xh + ((size_t)s1 * n + arow_c) * 16 + j1);
            af = (f16x8){a0[0], a0[1], a0[2], a0[3], a1[0], a1[1], a1[2], a1[3]};
        } else {
            const float* xr = Xf + (size_t)arow_c * 96;
            float4 u0 = *(const float4*)&xr[kk * 32 + lg * 8];
            float4 u1 = *(const float4*)&xr[kk * 32 + lg * 8 + 4];
            af[0] = (_Float16)u0.x; af[1] = (_Float16)u0.y;
            af[2] = (_Float16)u0.z; af[3] = (_Float16)u0.w;
            af[4] = (_Float16)u1.x; af[5] = (_Float16)u1.y;
            af[6] = (_Float16)u1.z; af[7] = (_Float16)u1.w;
        }
        #pragma unroll
        for (int t = 0; t < NT; ++t)
            acc[t] = __builtin_amdgcn_mfma_f32_16x16x32_f16(af, bfrag[t][kk], acc[t], 0, 0, 0);
    }

    // C/D: col = t*16+lr, row = row0 + lg*4 + i  (m89-verified map)
    #pragma unroll
    for (int i = 0; i < 4; ++i) {
        int r = row0 + lg * 4 + i;
        if (r < n) {
            float dv = dinv[r];
            #pragma unroll
            for (int t = 0; t < NT; ++t) {
                int cc = t * 16 + lr;
                __half hv = __float2half(acc[t][i] * dv);
                if (OUTSLICED) {
                    int sl = cc / 12;
                    int jj = cc - sl * 12;
                    Hout[((size_t)sl * n + r) * 16 + jj] = hv;
                } else {
                    Hout[(size_t)r * FOUT + cc] = hv;
                }
            }
        }
    }
}

// --- sliced aggregation, F=96: slice = blockIdx%8 (XCD-pinned) ----------------
// Wave = 8 nodes x 8 chains. Lane gathers its chain's 32B-padded row-slice
// (f16x8 + f16x4, both aligned), accumulates 12 feats with mix-FMA (w = tail
// mask), 3 shfl_xor rounds reduce chains. Chain-0 lane writes the node's
// 32B sliced fp16 output (dense, single-XCD lines) nontemporally.
template <bool SILU>
__global__ __launch_bounds__(256) void k_agg96s(const __half* __restrict__ Hs,
                                                const float* __restrict__ dinv,
                                                const int* __restrict__ rowptr,
                                                const int* __restrict__ adj,
                                                const float* __restrict__ bias,
                                                __half* __restrict__ OUT, int n) {
    const int s = blockIdx.x & 7;
    const int nb = blockIdx.x >> 3;
    const int l = threadIdx.x & 63;
    const int c = l & 7;
    const int ni = nb * 32 + (threadIdx.x >> 6) * 8 + (l >> 3);
    const int nic = ni < n ? ni : n - 1;
    const float dn = dinv[nic];
    const int e0 = rowptr[nic];
    const int deg = rowptr[nic + 1] - e0;
    const int cnt = deg + 1;  // +self
    const __half* __restrict__ tb = Hs + (size_t)s * n * 16;

    float acc[12];
    #pragma unroll
    for (int i = 0; i < 12; ++i) acc[i] = 0.f;

    for (int k0 = 0; k0 < cnt; k0 += 8) {
        int idx = k0 + c;
        int src = nic;                       // idx==0 -> self row
        int oe = idx - 1;
        if (oe >= 0 && oe < deg)
            src = __builtin_nontemporal_load(adj + e0 + oe);
        float wv = (idx < cnt) ? 1.f : 0.f;
        const __half* rp = tb + (size_t)src * 16;
        f16x8 v0 = *(const f16x8*)rp;          // 16B, 16B-aligned
        f16x4 v1 = *(const f16x4*)(rp + 8);    // 8B, aligned
        #pragma unroll
        for (int i = 0; i < 8; ++i) acc[i] = fmaf((float)v0[i], wv, acc[i]);
        #pragma unroll
        for (int i = 0; i < 4; ++i) acc[8 + i] = fmaf((float)v1[i], wv, acc[8 + i]);
    }

    #pragma unroll
    for (int i = 0; i < 12; ++i) {
        acc[i] += __shfl_xor(acc[i], 1, 64);
        acc[i] += __shfl_xor(acc[i], 2, 64);
        acc[i] += __shfl_xor(acc[i], 4, 64);
    }

    if (c == 0 && ni < n) {
        const float4* bv = (const float4*)(bias + s * 12);
        float4 b0 = bv[0], b1 = bv[1], b2 = bv[2];
        float o[12];
        o[0] = acc[0] * dn + b0.x;   o[1] = acc[1] * dn + b0.y;
        o[2] = acc[2] * dn + b0.z;   o[3] = acc[3] * dn + b0.w;
        o[4] = acc[4] * dn + b1.x;   o[5] = acc[5] * dn + b1.y;
        o[6] = acc[6] * dn + b1.z;   o[7] = acc[7] * dn + b1.w;
        o[8] = acc[8] * dn + b2.x;   o[9] = acc[9] * dn + b2.y;
        o[10] = acc[10] * dn + b2.z; o[11] = acc[11] * dn + b2.w;
        if (SILU) {
            #pragma unroll
            for (int j = 0; j < 12; ++j) o[j] = silu_f(o[j]);
        }
        f16x8 w0 = {(_Float16)o[0], (_Float16)o[1], (_Float16)o[2], (_Float16)o[3],
                    (_Float16)o[4], (_Float16)o[5], (_Float16)o[6], (_Float16)o[7]};
        f16x8 w1 = {(_Float16)o[8], (_Float16)o[9], (_Float16)o[10], (_Float16)o[11],
                    (_Float16)0.f, (_Float16)0.f, (_Float16)0.f, (_Float16)0.f};
        __half* op = OUT + ((size_t)s * n + ni) * 16;
        __builtin_nontemporal_store(w0, (f16x8*)op);
        __builtin_nontemporal_store(w1, (f16x8*)(op + 8));
    }
}

// --- aggregation, F=32, natural 64B rows (round-6 structure) ------------------
// 8-lane row groups; lane li loads f16x4 (8B). g = l>>3 owns one edge-chain.
__global__ __launch_bounds__(256) void k_agg32(const __half* __restrict__ Hp,
                                               const float* __restrict__ dinv,
                                               const int* __restrict__ rowptr,
                                               const int* __restrict__ adj,
                                               const float* __restrict__ bias,
                                               float* __restrict__ OUT, int n) {
    const int l = threadIdx.x & 63;
    const int node = blockIdx.x * 4 + (threadIdx.x >> 6);
    if (node >= n) return;
    const int g = l >> 3;
    const int li = l & 7;
    const float dn = dinv[node];
    const int e0 = rowptr[node], e1 = rowptr[node + 1];
    const f16x4* __restrict__ H4 = (const f16x4*)Hp;  // 8 f16x4 per row

    float acc[4] = {0.f, 0.f, 0.f, 0.f};

    {
        f16x4 v = H4[(size_t)node * 8 + li];
        float ws = (g == 0) ? 1.f : 0.f;
        #pragma unroll
        for (int i = 0; i < 4; ++i) acc[i] = fmaf((float)v[i], ws, acc[i]);
    }

    for (int e = e0; e < e1; e += 8) {
        int ai = e + (l & 7);
        int v_s = adj[ai < e1 ? ai : e1 - 1];
        int src = __shfl(v_s, g, 64);
        float w = (e + g < e1) ? 1.f : 0.f;
        f16x4 v = H4[(size_t)src * 8 + li];
        #pragma unroll
        for (int i = 0; i < 4; ++i) acc[i] = fmaf((float)v[i], w, acc[i]);
    }

    #pragma unroll
    for (int i = 0; i < 4; ++i) {
        acc[i] += __shfl_xor(acc[i], 8, 64);
        acc[i] += __shfl_xor(acc[i], 16, 64);
        acc[i] += __shfl_xor(acc[i], 32, 64);
    }

    if (l < 8) {  // lane li owns features 4li..4li+3
        float4 bv = ((const float4*)bias)[l];
        float4 o = make_float4(acc[0] * dn + bv.x, acc[1] * dn + bv.y,
                               acc[2] * dn + bv.z, acc[3] * dn + bv.w);
        ((float4*)(OUT + (size_t)node * 32))[l] = o;
    }
}

// --- per-graph max+mean pool (block per graph) --------------------------------
__global__ __launch_bounds__(256) void k_pool(const float* __restrict__ A,
                                              const int* __restrict__ gstart,
                                              float* __restrict__ pooled) {
    int g = blockIdx.x;
    int s0 = gstart[g], s1 = gstart[g + 1];
    int c = threadIdx.x & 31, k = threadIdx.x >> 5;
    float mx = -INFINITY, sm = 0.f;
    for (int nidx = s0 + k; nidx < s1; nidx += 8) {
        float v = A[(size_t)nidx * 32 + c];
        mx = fmaxf(mx, v);
        sm += v;
    }
    __shared__ float smx[8][32], ssm[8][32];
    smx[k][c] = mx;
    ssm[k][c] = sm;
    __syncthreads();
    if (threadIdx.x < 32) {
        float M = smx[0][c], S = ssm[0][c];
        #pragma unroll
        for (int kk = 1; kk < 8; ++kk) {
            M = fmaxf(M, smx[kk][c]);
            S += ssm[kk][c];
        }
        int cnt = s1 - s0;
        pooled[g * 64 + c] = M;
        pooled[g * 64 + 32 + c] = S / fmaxf((float)cnt, 1.0f);
    }
}

// --- row log_softmax over 64 values -------------------------------------------
__global__ __launch_bounds__(64) void k_lsm(const float* __restrict__ pooled,
                                            float* __restrict__ out) {
    int g = blockIdx.x;
    int l = threadIdx.x;
    float v = pooled[g * 64 + l];
    float m = v;
    #pragma unroll
    for (int o = 32; o > 0; o >>= 1) m = fmaxf(m, __shfl_xor(m, o, 64));
    float e = __expf(v - m);
    float s = e;
    #pragma unroll
    for (int o = 32; o > 0; o >>= 1) s += __shfl_xor(s, o, 64);
    out[g * 64 + l] = v - m - __logf(s);
}

// ---------------------------------------------------------------------------
extern "C" void kernel_launch(void* const* d_in, const int* in_sizes, int n_in,
                              void* d_out, int out_size, void* d_ws, size_t ws_size,
                              hipStream_t stream) {
    const float* x  = (const float*)d_in[0];
    const float* W0 = (const float*)d_in[1];
    const float* b0 = (const float*)d_in[2];
    const float* W1 = (const float*)d_in[3];
    const float* b1 = (const float*)d_in[4];
    const float* W2 = (const float*)d_in[5];
    const float* b2 = (const float*)d_in[6];
    const int* ei_raw    = (const int*)d_in[7];
    const int* batch_raw = (const int*)d_in[8];

    const int N = in_sizes[0] / 96;
    const int E = in_sizes[7] / 2;
    const int G = out_size / 64;
    const int NBUK = (N + 255) >> 8;          // 256 nodes/bucket, <=512 buckets
    float* out = (float*)d_out;

    char* ws = (char*)d_ws;
    size_t off = 0;
    auto alloc = [&](size_t bytes) -> void* {
        void* p = ws + off;
        off += (bytes + 255) & ~(size_t)255;
        return p;
    };
    __half*   HsT     = (__half*)alloc((size_t)N * 8 * 16 * 2); // sliced table (gemm out)
    __half*   AsT     = (__half*)alloc((size_t)N * 8 * 16 * 2); // sliced agg out
    __half*   Hp32    = (__half*)alloc((size_t)N * 32 * 2);     // layer-2 table, natural
    float*    D32     = (float*)alloc((size_t)N * 32 * 4);      // layer-2 agg out
    int*      e32     = (int*)alloc((size_t)2 * E * 4);
    int*      batch32 = (int*)alloc((size_t)N * 4);
    float*    dinv    = (float*)alloc((size_t)N * 4);
    int*      rowptr  = (int*)alloc((size_t)(N + 1) * 4);
    int*      adj     = (int*)alloc((size_t)E * 4);
    unsigned* ebuk    = (unsigned*)alloc((size_t)E * 4);        // bucket-sorted packed edges
    int*      bcnt    = (int*)alloc(512 * 4);
    int*      bstart  = (int*)alloc(513 * 4);
    int*      gcursor = (int*)alloc(512 * 4);
    int*      flag    = (int*)alloc(256);
    int*      gstart  = (int*)alloc((size_t)(G + 1) * 4);
    float*    pooled  = (float*)alloc((size_t)G * 64 * 4);
    __half*   WT0     = (__half*)alloc((size_t)96 * 96 * 2);    // W^T fp16
    __half*   WT1     = (__half*)alloc((size_t)96 * 96 * 2);
    __half*   WT2     = (__half*)alloc((size_t)32 * 96 * 2);

    (void)hipMemsetAsync(bcnt, 0, 512 * 4, stream);
    (void)hipMemsetAsync(gcursor, 0, 512 * 4, stream);

    // index dtype normalize
    k_detect<<<1, 256, 0, stream>>>(ei_raw, flag);
    k_convert<<<(2 * E + 255) / 256, 256, 0, stream>>>(ei_raw, e32, flag, 2 * E);
    k_convert<<<(N + 255) / 256, 256, 0, stream>>>(batch_raw, batch32, flag, N);

    // weight transpose+convert (tiny)
    k_wt<<<(96 * 96 + 255) / 256, 256, 0, stream>>>(W0, WT0, 96);
    k_wt<<<(96 * 96 + 255) / 256, 256, 0, stream>>>(W1, WT1, 96);
    k_wt<<<(32 * 96 + 255) / 256, 256, 0, stream>>>(W2, WT2, 32);

    // CSR via bucket sort
    const int P2B = (E + 8191) / 8192;
    k_p1hist<<<P2B, 512, 0, stream>>>(e32 + E, bcnt, E, NBUK);
    k_bscan<<<1, 512, 0, stream>>>(bcnt, bstart, NBUK, E);
    k_p2scatter<<<P2B, 512, 0, stream>>>(e32, bstart, gcursor, ebuk, E, NBUK);
    k_p3sort<<<NBUK, 256, 0, stream>>>(ebuk, bstart, adj, rowptr, dinv, N, E);
    k_gstart<<<1, 256, 0, stream>>>(batch32, gstart, N, G);

    const int GB = (N + 63) / 64;
    const int NBN = (N + 31) / 32;    // 32 nodes per sliced-agg block
    const int AGB = NBN * 8;          // x8 slices, slice = bid%8 (XCD-pinned)
    const int AB32 = (N + 3) / 4;     // 4 nodes per block (round-6 agg32)

    // layer 0: A = x fp32 natural, out sliced
    k_gemm_mfma<96, false, true><<<GB, 256, 0, stream>>>(x, (const __half*)nullptr, WT0, dinv, HsT, N);
    k_agg96s<true><<<AGB, 256, 0, stream>>>(HsT, dinv, rowptr, adj, b0, AsT, N);
    // layer 1: A = AsT sliced fp16, out sliced
    k_gemm_mfma<96, true, true><<<GB, 256, 0, stream>>>((const float*)nullptr, AsT, WT1, dinv, HsT, N);
    k_agg96s<true><<<AGB, 256, 0, stream>>>(HsT, dinv, rowptr, adj, b1, AsT, N);
    // layer 2: A = AsT sliced fp16, out natural 64B rows
    k_gemm_mfma<32, true, false><<<GB, 256, 0, stream>>>((const float*)nullptr, AsT, WT2, dinv, Hp32, N);
    k_agg32<<<AB32, 256, 0, stream>>>(Hp32, dinv, rowptr, adj, b2, D32, N);

    // pooling + log_softmax
    k_pool<<<G, 256, 0, stream>>>(D32, gstart, pooled);
    k_lsm<<<G, 64, 0, stream>>>(pooled, out);
}

// Round 10
// 262.802 us; speedup vs baseline: 1.5736x; 1.2320x over previous
//
#include <hip/hip_runtime.h>
#include <hip/hip_fp16.h>
#include <math.h>

// ---------------------------------------------------------------------------
// GCN: 3x (MFMA-fp16 GEMM -> sym-normalized neighbor aggregate) with SiLU,
// then per-graph max+mean pool and log_softmax.
// CSR build = 2-pass bucket sort (round-6 structure).
// Round 10: revert agg96 to the proven un-sliced 16-lane row-group structure
// (round-6, 53us) -- slicing replicated per-edge fixed costs 8x and lost.
// Keep round-9's validated fp16 inter-kernel dataflow:
//   agg output = fp16 natural [N][96]; GEMM layers 1/2 read fp16 A directly.
// Gather tables stay fp16 256B-padded rows (f16x8 gathers, v_fma_mix accum).
// ---------------------------------------------------------------------------

typedef _Float16 f16x8 __attribute__((ext_vector_type(8)));
typedef _Float16 f16x4 __attribute__((ext_vector_type(4)));
typedef float f32x4 __attribute__((ext_vector_type(4)));

static __device__ __forceinline__ float silu_f(float v) {
    return v / (1.0f + __expf(-v));
}

// --- int64-vs-int32 input detection -----------------------------------------
__global__ __launch_bounds__(256) void k_detect(const int* __restrict__ raw,
                                                int* __restrict__ flag) {
    __shared__ int anynz;
    if (threadIdx.x == 0) anynz = 0;
    __syncthreads();
    if (raw[2 * threadIdx.x + 1] != 0) anynz = 1;  // benign race, same value
    __syncthreads();
    if (threadIdx.x == 0) *flag = (anynz ? 0 : 1); // 1 => int64
}

__global__ __launch_bounds__(256) void k_convert(const int* __restrict__ raw,
                                                 int* __restrict__ out,
                                                 const int* __restrict__ flag,
                                                 int count) {
    int i = blockIdx.x * 256 + threadIdx.x;
    if (i < count) out[i] = flag[0] ? raw[2 * i] : raw[i];
}

// --- CSR pass 1: bucket histogram (bucket = dst>>8, <=512 buckets) -----------
__global__ __launch_bounds__(512) void k_p1hist(const int* __restrict__ dst,
                                                int* __restrict__ bcnt,
                                                int E, int nbuk) {
    __shared__ int hs[512];
    const int t = threadIdx.x;
    hs[t] = 0;
    __syncthreads();
    const int base = blockIdx.x * 8192;
    const int lim = min(base + 8192, E);
    for (int j = base + t; j < lim; j += 512)
        atomicAdd(&hs[dst[j] >> 8], 1);
    __syncthreads();
    if (t < nbuk && hs[t]) atomicAdd(&bcnt[t], hs[t]);
}

// --- CSR pass 1b: exclusive scan of bucket counts -> bstart ------------------
__global__ __launch_bounds__(512) void k_bscan(const int* __restrict__ bcnt,
                                               int* __restrict__ bstart,
                                               int nbuk, int E) {
    __shared__ int lds[512];
    int t = threadIdx.x;
    int v = (t < nbuk) ? bcnt[t] : 0;
    lds[t] = v;
    __syncthreads();
    for (int off = 1; off < 512; off <<= 1) {
        int y = (t >= off) ? lds[t - off] : 0;
        __syncthreads();
        lds[t] += y;
        __syncthreads();
    }
    if (t < nbuk) bstart[t] = lds[t] - v;
    if (t == 0) bstart[nbuk] = E;
}

// --- CSR pass 2: bucket scatter, block-staged ---------------------------------
__global__ __launch_bounds__(512) void k_p2scatter(const int* __restrict__ e32,
                                                   const int* __restrict__ bstart,
                                                   int* __restrict__ gcursor,
                                                   unsigned* __restrict__ ebuk,
                                                   int E, int nbuk) {
    __shared__ int hs[512], sc[512], lexcl[512], pl[512], gb[512];
    __shared__ unsigned stg[8192];
    __shared__ unsigned short stb[8192];
    const int t = threadIdx.x;
    const int base = blockIdx.x * 8192;
    const int len = min(8192, E - base);
    const int* __restrict__ dstp = e32 + E;

    hs[t] = 0;
    __syncthreads();
    for (int j = t; j < len; j += 512)
        atomicAdd(&hs[dstp[base + j] >> 8], 1);
    __syncthreads();

    int cv = (t < nbuk) ? hs[t] : 0;
    sc[t] = cv;
    __syncthreads();
    for (int off = 1; off < 512; off <<= 1) {
        int y = (t >= off) ? sc[t - off] : 0;
        __syncthreads();
        sc[t] += y;
        __syncthreads();
    }
    int ex = sc[t] - cv;
    if (t < nbuk) {
        lexcl[t] = ex;
        pl[t] = ex;
        gb[t] = cv ? atomicAdd(&gcursor[t], cv) : 0;
    }
    __syncthreads();

    for (int j = t; j < len; j += 512) {
        int d = dstp[base + j];
        int s = e32[base + j];
        int b = d >> 8;
        int slot = atomicAdd(&pl[b], 1);
        stg[slot] = ((unsigned)s << 8) | (unsigned)(d & 255);
        stb[slot] = (unsigned short)b;
    }
    __syncthreads();

    for (int s2 = t; s2 < len; s2 += 512) {
        int b = stb[s2];
        int gpos = bstart[b] + gb[b] + (s2 - lexcl[b]);
        ebuk[gpos] = stg[s2];
    }
}

// --- CSR pass 3: per-bucket counting sort -> adj, rowptr, dinv ----------------
__global__ __launch_bounds__(256) void k_p3sort(const unsigned* __restrict__ ebuk,
                                                const int* __restrict__ bstart,
                                                int* __restrict__ adj,
                                                int* __restrict__ rowptr,
                                                float* __restrict__ dinv,
                                                int n, int E) {
    const int b = blockIdx.x;
    const int t = threadIdx.x;
    const int s0 = bstart[b], s1 = bstart[b + 1];
    __shared__ int cs[256], pl[256];
    cs[t] = 0;
    __syncthreads();
    for (int j = s0 + t; j < s1; j += 256)
        atomicAdd(&cs[ebuk[j] & 255], 1);
    __syncthreads();
    int cv = cs[t];
    pl[t] = cv;
    __syncthreads();
    for (int off = 1; off < 256; off <<= 1) {
        int y = (t >= off) ? pl[t - off] : 0;
        __syncthreads();
        pl[t] += y;
        __syncthreads();
    }
    int ex = pl[t] - cv;
    __syncthreads();
    pl[t] = ex;
    int node = (b << 8) + t;
    if (node < n) {
        rowptr[node] = s0 + ex;
        dinv[node] = rsqrtf((float)cv + 1.0f);  // +1 self loop
    }
    if (b == 0 && t == 0) rowptr[n] = E;
    __syncthreads();
    for (int j = s0 + t; j < s1; j += 256) {
        unsigned p = ebuk[j];
        int slot = atomicAdd(&pl[p & 255], 1);
        adj[s0 + slot] = (int)(p >> 8);
    }
}

// --- per-graph boundaries (batch is sorted) -----------------------------------
__global__ __launch_bounds__(256) void k_gstart(const int* __restrict__ batch,
                                                int* __restrict__ gstart,
                                                int n, int G) {
    int t = threadIdx.x;
    if (t > G) return;
    int lo = 0, hi = n;
    while (lo < hi) {
        int mid = (lo + hi) >> 1;
        if (batch[mid] < t) lo = mid + 1; else hi = mid;
    }
    gstart[t] = lo;
}

// --- W transpose + fp16 convert: WT[n][k] = fp16(W[k][n]) ---------------------
__global__ __launch_bounds__(256) void k_wt(const float* __restrict__ W,
                                            __half* __restrict__ WT, int fout) {
    int idx = blockIdx.x * 256 + threadIdx.x;
    if (idx < fout * 96) {
        int nn = idx / 96, kk = idx - nn * 96;
        WT[idx] = __float2half(W[kk * fout + nn]);
    }
}

// --- MFMA GEMM: H[r,:] = fp16( dinv[r] * (A[r,:96] @ W) ), LDS-free ----------
// A: fp32 natural (AHALF=0, layer 0 input x) or fp16 natural 96-stride
// (AHALF=1, agg output). Output: fp16, HSTRIDE-padded rows (gather table).
// A and B share identical per-lane k-addressing -> the hardware k->slot map
// cancels (dot products are k-permutation invariant).
template <int FOUT, int HSTRIDE, bool AHALF>
__global__ __launch_bounds__(256) void k_gemm_mfma(const float* __restrict__ Xf,
                                                   const __half* __restrict__ Xh,
                                                   const __half* __restrict__ WT,
                                                   const float* __restrict__ dinv,
                                                   __half* __restrict__ H, int n) {
    const int l = threadIdx.x & 63;
    const int w = threadIdx.x >> 6;
    const int row0 = blockIdx.x * 64 + w * 16;
    const int lr = l & 15, lg = l >> 4;
    constexpr int NT = FOUT / 16;

    f16x8 bfrag[NT][3];
    #pragma unroll
    for (int t = 0; t < NT; ++t)
        #pragma unroll
        for (int kk = 0; kk < 3; ++kk)
            bfrag[t][kk] = *(const f16x8*)&WT[(t * 16 + lr) * 96 + kk * 32 + lg * 8];

    f32x4 acc[NT];
    #pragma unroll
    for (int t = 0; t < NT; ++t) acc[t] = (f32x4){0.f, 0.f, 0.f, 0.f};

    int arow = row0 + lr;
    int arow_c = arow < n ? arow : n - 1;  // clamp; garbage rows never stored

    #pragma unroll
    for (int kk = 0; kk < 3; ++kk) {
        f16x8 af;
        if (AHALF) {
            af = *(const f16x8*)(Xh + (size_t)arow_c * 96 + kk * 32 + lg * 8);
        } else {
            const float* xr = Xf + (size_t)arow_c * 96;
            float4 u0 = *(const float4*)&xr[kk * 32 + lg * 8];
            float4 u1 = *(const float4*)&xr[kk * 32 + lg * 8 + 4];
            af[0] = (_Float16)u0.x; af[1] = (_Float16)u0.y;
            af[2] = (_Float16)u0.z; af[3] = (_Float16)u0.w;
            af[4] = (_Float16)u1.x; af[5] = (_Float16)u1.y;
            af[6] = (_Float16)u1.z; af[7] = (_Float16)u1.w;
        }
        #pragma unroll
        for (int t = 0; t < NT; ++t)
            acc[t] = __builtin_amdgcn_mfma_f32_16x16x32_f16(af, bfrag[t][kk], acc[t], 0, 0, 0);
    }

    // C/D: col = t*16+lr, row = row0 + lg*4 + i  (m89-verified map)
    #pragma unroll
    for (int i = 0; i < 4; ++i) {
        int r = row0 + lg * 4 + i;
        if (r < n) {
            float dv = dinv[r];
            #pragma unroll
            for (int t = 0; t < NT; ++t)
                H[(size_t)r * HSTRIDE + t * 16 + lr] = __float2half(acc[t][i] * dv);
        }
    }
}

// --- aggregation, F=96 (table rows padded to 128 fp16 = 256B) -----------------
// Round-6 proven structure. One wave per node. Quarter q = l>>4 owns one
// edge-chain; lane li = l&15 loads f16x8 (16B) -> feats 8li..8li+7 (li<12
// real). 8 edges/iter = 2 gathers/lane; tail masked via the w multiplier
// (fuses into v_fma_mix_f32). Output fp16 natural [n][96].
template <bool SILU>
__global__ __launch_bounds__(256) void k_agg96(const __half* __restrict__ Hp,
                                               const float* __restrict__ dinv,
                                               const int* __restrict__ rowptr,
                                               const int* __restrict__ adj,
                                               const float* __restrict__ bias,
                                               __half* __restrict__ OUT, int n) {
    const int l = threadIdx.x & 63;
    const int node = blockIdx.x * 4 + (threadIdx.x >> 6);
    if (node >= n) return;
    const int q = l >> 4;
    const int li = l & 15;
    const float dn = dinv[node];
    const int e0 = rowptr[node], e1 = rowptr[node + 1];
    const f16x8* __restrict__ H8 = (const f16x8*)Hp;  // 16 f16x8 per row

    float acc[8] = {0.f, 0.f, 0.f, 0.f, 0.f, 0.f, 0.f, 0.f};

    // self row (counted once, quarter 0)
    {
        f16x8 v = H8[(size_t)node * 16 + li];
        float ws = (q == 0) ? 1.f : 0.f;
        #pragma unroll
        for (int i = 0; i < 8; ++i) acc[i] = fmaf((float)v[i], ws, acc[i]);
    }

    for (int e = e0; e < e1; e += 8) {
        int ai = e + (l & 7);
        int v_s = adj[ai < e1 ? ai : e1 - 1];  // coalesced: 8 edge srcs
        #pragma unroll
        for (int j = 0; j < 2; ++j) {
            int c = 4 * j + q;
            int s = __shfl(v_s, c, 64);
            float w = (e + c < e1) ? 1.f : 0.f;
            f16x8 v = H8[(size_t)s * 16 + li];
            #pragma unroll
            for (int i = 0; i < 8; ++i) acc[i] = fmaf((float)v[i], w, acc[i]);
        }
    }

    // reduce across quarters
    #pragma unroll
    for (int i = 0; i < 8; ++i) {
        acc[i] += __shfl_xor(acc[i], 16, 64);
        acc[i] += __shfl_xor(acc[i], 32, 64);
    }

    if (l < 12) {  // q==0, li<12: lane li owns features 8li..8li+7
        float4 bv0 = ((const float4*)bias)[2 * l];
        float4 bv1 = ((const float4*)bias)[2 * l + 1];
        float o0 = acc[0] * dn + bv0.x, o1 = acc[1] * dn + bv0.y;
        float o2 = acc[2] * dn + bv0.z, o3 = acc[3] * dn + bv0.w;
        float o4 = acc[4] * dn + bv1.x, o5 = acc[5] * dn + bv1.y;
        float o6 = acc[6] * dn + bv1.z, o7 = acc[7] * dn + bv1.w;
        if (SILU) {
            o0 = silu_f(o0); o1 = silu_f(o1); o2 = silu_f(o2); o3 = silu_f(o3);
            o4 = silu_f(o4); o5 = silu_f(o5); o6 = silu_f(o6); o7 = silu_f(o7);
        }
        f16x8 wv = {(_Float16)o0, (_Float16)o1, (_Float16)o2, (_Float16)o3,
                    (_Float16)o4, (_Float16)o5, (_Float16)o6, (_Float16)o7};
        *(f16x8*)(OUT + (size_t)node * 96 + l * 8) = wv;
    }
}

// --- aggregation, F=32, natural 64B rows (round-6 structure) ------------------
// 8-lane row groups; lane li loads f16x4 (8B). g = l>>3 owns one edge-chain.
__global__ __launch_bounds__(256) void k_agg32(const __half* __restrict__ Hp,
                                               const float* __restrict__ dinv,
                                               const int* __restrict__ rowptr,
                                               const int* __restrict__ adj,
                                               const float* __restrict__ bias,
                                               float* __restrict__ OUT, int n) {
    const int l = threadIdx.x & 63;
    const int node = blockIdx.x * 4 + (threadIdx.x >> 6);
    if (node >= n) return;
    const int g = l >> 3;
    const int li = l & 7;
    const float dn = dinv[node];
    const int e0 = rowptr[node], e1 = rowptr[node + 1];
    const f16x4* __restrict__ H4 = (const f16x4*)Hp;  // 8 f16x4 per row

    float acc[4] = {0.f, 0.f, 0.f, 0.f};

    {
        f16x4 v = H4[(size_t)node * 8 + li];
        float ws = (g == 0) ? 1.f : 0.f;
        #pragma unroll
        for (int i = 0; i < 4; ++i) acc[i] = fmaf((float)v[i], ws, acc[i]);
    }

    for (int e = e0; e < e1; e += 8) {
        int ai = e + (l & 7);
        int v_s = adj[ai < e1 ? ai : e1 - 1];
        int src = __shfl(v_s, g, 64);
        float w = (e + g < e1) ? 1.f : 0.f;
        f16x4 v = H4[(size_t)src * 8 + li];
        #pragma unroll
        for (int i = 0; i < 4; ++i) acc[i] = fmaf((float)v[i], w, acc[i]);
    }

    #pragma unroll
    for (int i = 0; i < 4; ++i) {
        acc[i] += __shfl_xor(acc[i], 8, 64);
        acc[i] += __shfl_xor(acc[i], 16, 64);
        acc[i] += __shfl_xor(acc[i], 32, 64);
    }

    if (l < 8) {  // lane li owns features 4li..4li+3
        float4 bv = ((const float4*)bias)[l];
        float4 o = make_float4(acc[0] * dn + bv.x, acc[1] * dn + bv.y,
                               acc[2] * dn + bv.z, acc[3] * dn + bv.w);
        ((float4*)(OUT + (size_t)node * 32))[l] = o;
    }
}

// --- per-graph max+mean pool (block per graph) --------------------------------
__global__ __launch_bounds__(256) void k_pool(const float* __restrict__ A,
                                              const int* __restrict__ gstart,
                                              float* __restrict__ pooled) {
    int g = blockIdx.x;
    int s0 = gstart[g], s1 = gstart[g + 1];
    int c = threadIdx.x & 31, k = threadIdx.x >> 5;
    float mx = -INFINITY, sm = 0.f;
    for (int nidx = s0 + k; nidx < s1; nidx += 8) {
        float v = A[(size_t)nidx * 32 + c];
        mx = fmaxf(mx, v);
        sm += v;
    }
    __shared__ float smx[8][32], ssm[8][32];
    smx[k][c] = mx;
    ssm[k][c] = sm;
    __syncthreads();
    if (threadIdx.x < 32) {
        float M = smx[0][c], S = ssm[0][c];
        #pragma unroll
        for (int kk = 1; kk < 8; ++kk) {
            M = fmaxf(M, smx[kk][c]);
            S += ssm[kk][c];
        }
        int cnt = s1 - s0;
        pooled[g * 64 + c] = M;
        pooled[g * 64 + 32 + c] = S / fmaxf((float)cnt, 1.0f);
    }
}

// --- row log_softmax over 64 values -------------------------------------------
__global__ __launch_bounds__(64) void k_lsm(const float* __restrict__ pooled,
                                            float* __restrict__ out) {
    int g = blockIdx.x;
    int l = threadIdx.x;
    float v = pooled[g * 64 + l];
    float m = v;
    #pragma unroll
    for (int o = 32; o > 0; o >>= 1) m = fmaxf(m, __shfl_xor(m, o, 64));
    float e = __expf(v - m);
    float s = e;
    #pragma unroll
    for (int o = 32; o > 0; o >>= 1) s += __shfl_xor(s, o, 64);
    out[g * 64 + l] = v - m - __logf(s);
}

// ---------------------------------------------------------------------------
extern "C" void kernel_launch(void* const* d_in, const int* in_sizes, int n_in,
                              void* d_out, int out_size, void* d_ws, size_t ws_size,
                              hipStream_t stream) {
    const float* x  = (const float*)d_in[0];
    const float* W0 = (const float*)d_in[1];
    const float* b0 = (const float*)d_in[2];
    const float* W1 = (const float*)d_in[3];
    const float* b1 = (const float*)d_in[4];
    const float* W2 = (const float*)d_in[5];
    const float* b2 = (const float*)d_in[6];
    const int* ei_raw    = (const int*)d_in[7];
    const int* batch_raw = (const int*)d_in[8];

    const int N = in_sizes[0] / 96;
    const int E = in_sizes[7] / 2;
    const int G = out_size / 64;
    const int NBUK = (N + 255) >> 8;          // 256 nodes/bucket, <=512 buckets
    float* out = (float*)d_out;

    char* ws = (char*)d_ws;
    size_t off = 0;
    auto alloc = [&](size_t bytes) -> void* {
        void* p = ws + off;
        off += (bytes + 255) & ~(size_t)255;
        return p;
    };
    __half*   Hp96    = (__half*)alloc((size_t)N * 128 * 2);  // gather table, 256B rows
    __half*   As16    = (__half*)alloc((size_t)N * 96 * 2);   // agg out, fp16 natural
    __half*   Hp32    = (__half*)alloc((size_t)N * 32 * 2);   // layer-2 table, 64B rows
    float*    D32     = (float*)alloc((size_t)N * 32 * 4);    // layer-2 agg out
    int*      e32     = (int*)alloc((size_t)2 * E * 4);
    int*      batch32 = (int*)alloc((size_t)N * 4);
    float*    dinv    = (float*)alloc((size_t)N * 4);
    int*      rowptr  = (int*)alloc((size_t)(N + 1) * 4);
    int*      adj     = (int*)alloc((size_t)E * 4);
    unsigned* ebuk    = (unsigned*)alloc((size_t)E * 4);      // bucket-sorted packed edges
    int*      bcnt    = (int*)alloc(512 * 4);
    int*      bstart  = (int*)alloc(513 * 4);
    int*      gcursor = (int*)alloc(512 * 4);
    int*      flag    = (int*)alloc(256);
    int*      gstart  = (int*)alloc((size_t)(G + 1) * 4);
    float*    pooled  = (float*)alloc((size_t)G * 64 * 4);
    __half*   WT0     = (__half*)alloc((size_t)96 * 96 * 2);  // W^T fp16
    __half*   WT1     = (__half*)alloc((size_t)96 * 96 * 2);
    __half*   WT2     = (__half*)alloc((size_t)32 * 96 * 2);

    (void)hipMemsetAsync(bcnt, 0, 512 * 4, stream);
    (void)hipMemsetAsync(gcursor, 0, 512 * 4, stream);

    // index dtype normalize
    k_detect<<<1, 256, 0, stream>>>(ei_raw, flag);
    k_convert<<<(2 * E + 255) / 256, 256, 0, stream>>>(ei_raw, e32, flag, 2 * E);
    k_convert<<<(N + 255) / 256, 256, 0, stream>>>(batch_raw, batch32, flag, N);

    // weight transpose+convert (tiny)
    k_wt<<<(96 * 96 + 255) / 256, 256, 0, stream>>>(W0, WT0, 96);
    k_wt<<<(96 * 96 + 255) / 256, 256, 0, stream>>>(W1, WT1, 96);
    k_wt<<<(32 * 96 + 255) / 256, 256, 0, stream>>>(W2, WT2, 32);

    // CSR via bucket sort
    const int P2B = (E + 8191) / 8192;
    k_p1hist<<<P2B, 512, 0, stream>>>(e32 + E, bcnt, E, NBUK);
    k_bscan<<<1, 512, 0, stream>>>(bcnt, bstart, NBUK, E);
    k_p2scatter<<<P2B, 512, 0, stream>>>(e32, bstart, gcursor, ebuk, E, NBUK);
    k_p3sort<<<NBUK, 256, 0, stream>>>(ebuk, bstart, adj, rowptr, dinv, N, E);
    k_gstart<<<1, 256, 0, stream>>>(batch32, gstart, N, G);

    const int GB = (N + 63) / 64;
    const int AB = (N + 3) / 4;   // 4 nodes per agg block

    // layer 0: A = x fp32
    k_gemm_mfma<96, 128, false><<<GB, 256, 0, stream>>>(x, (const __half*)nullptr, WT0, dinv, Hp96, N);
    k_agg96<true><<<AB, 256, 0, stream>>>(Hp96, dinv, rowptr, adj, b0, As16, N);
    // layer 1: A = As16 fp16
    k_gemm_mfma<96, 128, true><<<GB, 256, 0, stream>>>((const float*)nullptr, As16, WT1, dinv, Hp96, N);
    k_agg96<true><<<AB, 256, 0, stream>>>(Hp96, dinv, rowptr, adj, b1, As16, N);
    // layer 2: A = As16 fp16
    k_gemm_mfma<32, 32, true><<<GB, 256, 0, stream>>>((const float*)nullptr, As16, WT2, dinv, Hp32, N);
    k_agg32<<<AB, 256, 0, stream>>>(Hp32, dinv, rowptr, adj, b2, D32, N);

    // pooling + log_softmax
    k_pool<<<G, 256, 0, stream>>>(D32, gstart, pooled);
    k_lsm<<<G, 64, 0, stream>>>(pooled, out);
}